// Round 3
// baseline (465.149 us; speedup 1.0000x reference)
//
#include <hip/hip_runtime.h>

// SpMM: out[b,m] = bias[m] + sum_{e: dst[e]==m} values[e] * x[b, src[e]]
// B=32, N=M=50000, E=1600000.
//
// R3: coarse bucketing (dst>>7, K=391 buckets of 128 rows).
//   count (LDS-privatized) -> tiny scan (K entries) -> fill (LDS-staged,
//   grouped flush, per-block-per-bucket reservations) -> accum (LDS fp32
//   accumulator per bucket, LDS atomics, fused bias + transpose on output).
// R1 lesson: global fp32 atomics write through to HBM (204.8 MB).
// R2 lesson: random 8B global scatter costs a 64B line each (101 MB), and a
//            single-block 50k scan serializes on one CU.

#define BATCH  32
#define ROWB   128            // dst rows per bucket
#define KP     512            // padded max bucket count (M <= 65536)
#define EPB    8192           // edges per fill block
#define FILL_T 512
#define ACC_T  512

// ---- x (B,N) -> xt (N,B), LDS tiled ----
__global__ void k_transpose_x(const float* __restrict__ x, float* __restrict__ xt, int N) {
    __shared__ float tile[32][33];
    const int n0 = blockIdx.x * 32;
    const int tx = threadIdx.x;
    const int ty = threadIdx.y;
    #pragma unroll
    for (int k = 0; k < 4; ++k) {
        const int b = ty + 8 * k;
        const int n = n0 + tx;
        tile[tx][b] = (n < N) ? x[(size_t)b * N + n] : 0.0f;
    }
    __syncthreads();
    #pragma unroll
    for (int k = 0; k < 4; ++k) {
        const int n = n0 + ty + 8 * k;
        if (n < N) xt[(size_t)n * BATCH + tx] = tile[ty + 8 * k][tx];
    }
}

// ---- bucket counts (LDS-privatized histogram over K buckets) ----
__global__ void k_count(const int* __restrict__ idx, int* __restrict__ cnt, int E, int K) {
    __shared__ int h[KP];
    for (int i = threadIdx.x; i < K; i += blockDim.x) h[i] = 0;
    __syncthreads();
    const int stride = gridDim.x * blockDim.x;
    for (int e = blockIdx.x * blockDim.x + threadIdx.x; e < E; e += stride)
        atomicAdd(&h[idx[E + e] >> 7], 1);
    __syncthreads();
    for (int i = threadIdx.x; i < K; i += blockDim.x)
        if (h[i]) atomicAdd(&cnt[i], h[i]);
}

// ---- exclusive scan over K (<=512) bucket counts; one block of 512 ----
__global__ void k_scan(const int* __restrict__ cnt, int* __restrict__ start,
                       int* __restrict__ cursor, int K, int E) {
    __shared__ int sa[KP], sb[KP];
    const int t = threadIdx.x;               // 512 threads
    const int v = (t < K) ? cnt[t] : 0;
    sa[t] = v;
    __syncthreads();
    int* a = sa; int* b = sb;
    for (int off = 1; off < KP; off <<= 1) {
        b[t] = a[t] + ((t >= off) ? a[t - off] : 0);
        __syncthreads();
        int* tmp = a; a = b; b = tmp;
    }
    const int excl = a[t] - v;               // a = inclusive scan
    if (t < K) { start[t] = excl; cursor[t] = excl; }
    if (t == K - 1) start[K] = a[t];         // == E
}

// ---- fill: LDS-staged grouping by bucket, grouped coalesced flush ----
__global__ void k_fill(const int* __restrict__ idx, const float* __restrict__ values,
                       int* __restrict__ cursor, int2* __restrict__ records, int E, int K) {
    __shared__ int2 stage[EPB];              // 64 KB
    __shared__ int sa[KP], sb[KP];           // scan double-buffer
    __shared__ int lscan[KP + 1];
    __shared__ int lgbase[KP];

    const int t = threadIdx.x;               // 512
    const int base = blockIdx.x * EPB;
    const int total = min(EPB, E - base);

    sa[t] = 0;
    __syncthreads();
    // phase 1: local histogram
    for (int i = t; i < total; i += FILL_T)
        atomicAdd(&sa[idx[E + base + i] >> 7], 1);
    __syncthreads();
    const int myc = sa[t];                   // this thread's bucket count
    __syncthreads();
    // Hillis-Steele inclusive scan over KP entries
    int* a = sa; int* b = sb;
    for (int off = 1; off < KP; off <<= 1) {
        b[t] = a[t] + ((t >= off) ? a[t - off] : 0);
        __syncthreads();
        int* tmp = a; a = b; b = tmp;
    }
    lscan[t] = a[t] - myc;                   // exclusive; == total for t >= K
    if (t == 0) lscan[KP] = total;
    // reserve global range for this (block,bucket); reuse dead scan buffer as lcur
    int* lcur = b;
    lcur[t] = 0;
    lgbase[t] = (t < K && myc > 0) ? atomicAdd(&cursor[t], myc) : 0;
    __syncthreads();
    // phase 2: re-read edges, place grouped-by-bucket into LDS staging
    for (int i = t; i < total; i += FILL_T) {
        const int e = base + i;
        const int src = idx[e];
        const int dst = idx[E + e];
        const float v = values[e];
        const int bk = dst >> 7;
        const int pos = lscan[bk] + atomicAdd(&lcur[bk], 1);
        stage[pos] = make_int2(src | ((dst & 127) << 16), __float_as_int(v));
    }
    __syncthreads();
    // phase 3: flush — consecutive staging slots within a bucket map to
    // consecutive global addresses (chunks of ~EPB/K records)
    for (int i = t; i < total; i += FILL_T) {
        int bpos = 0;
        #pragma unroll
        for (int s = 256; s > 0; s >>= 1) {
            const int nb = bpos + s;
            if (nb < KP && lscan[nb] <= i) bpos = nb;
        }
        records[lgbase[bpos] + (i - lscan[bpos])] = stage[i];
    }
}

// ---- accum: one block per bucket; LDS fp32 accumulator; fused bias+transpose ----
__global__ void k_accum(const float* __restrict__ xt, const int2* __restrict__ records,
                        const int* __restrict__ start, const float* __restrict__ bias,
                        float* __restrict__ out, int M) {
    __shared__ float acc[ROWB * 33];         // +1 pad: conflict-free both phases
    const int t = threadIdx.x;               // 512
    const int bk = blockIdx.x;
    for (int i = t; i < ROWB * 33; i += ACC_T) acc[i] = 0.0f;
    __syncthreads();
    const int jb = start[bk], je = start[bk + 1];
    const int bb = t & 31;
    for (int j = jb + (t >> 5); j < je; j += ACC_T / 32) {
        const int2 r = records[j];           // 8B broadcast across 32 lanes
        const int src = r.x & 0xFFFF;
        const int dl  = (r.x >> 16) & 127;
        const float v = __int_as_float(r.y);
        atomicAdd(&acc[dl * 33 + bb], v * xt[((size_t)src << 5) + bb]);  // ds_add_f32
    }
    __syncthreads();
    const int m0 = bk * ROWB;
    for (int i = t; i < ROWB * BATCH; i += ACC_T) {
        const int mm = i & (ROWB - 1);
        const int bo = i >> 7;               // i / ROWB
        const int m  = m0 + mm;
        if (m < M) out[(size_t)bo * M + m] = acc[mm * 33 + bo] + bias[m];
    }
}

extern "C" void kernel_launch(void* const* d_in, const int* in_sizes, int n_in,
                              void* d_out, int out_size, void* d_ws, size_t ws_size,
                              hipStream_t stream) {
    const float* x      = (const float*)d_in[0];  // (B,N,1) fp32
    const float* values = (const float*)d_in[1];  // (E,)    fp32
    const float* bias   = (const float*)d_in[2];  // (M,1)   fp32
    const int*   idx    = (const int*)d_in[3];    // (2,E)   int32

    const int N = in_sizes[0] / BATCH;   // 50000
    const int E = in_sizes[3] / 2;       // 1600000
    const int M = in_sizes[2];           // 50000
    const int K = (M + ROWB - 1) / ROWB; // 391

    float* out = (float*)d_out;

    // workspace: records (E int2, 12.8 MB) | xt (N*32 f32, 6.4 MB) | cnt | start | cursor
    char* p = (char*)d_ws;
    int2*  records = (int2*)p;           p += (size_t)E * sizeof(int2);
    float* xt      = (float*)p;          p += (size_t)N * BATCH * sizeof(float);
    int*   cnt     = (int*)p;            p += (size_t)K * sizeof(int);
    int*   start   = (int*)p;            p += (size_t)(K + 1) * sizeof(int);
    int*   cursor  = (int*)p;

    hipMemsetAsync(cnt, 0, (size_t)K * sizeof(int), stream);

    dim3 tblk(32, 8);
    k_transpose_x<<<(N + 31) / 32, tblk, 0, stream>>>(x, xt, N);
    k_count<<<256, 256, 0, stream>>>(idx, cnt, E, K);
    k_scan<<<1, KP, 0, stream>>>(cnt, start, cursor, K, E);
    k_fill<<<(E + EPB - 1) / EPB, FILL_T, 0, stream>>>(idx, values, cursor, records, E, K);
    k_accum<<<K, ACC_T, 0, stream>>>(xt, records, start, bias, out, M);
}

// Round 4
// 411.123 us; speedup vs baseline: 1.1314x; 1.1314x over previous
//
#include <hip/hip_runtime.h>

// SpMM: out[b,m] = bias[m] + sum_{e: dst[e]==m} values[e] * x[b, src[e]]
// B=32, N=M=50000, E=1600000.
//
// R4: keep R3's CSR-by-bucket build (count/scan/fill); rewrite accum for
// latency hiding: (bucket x batch-octet) grid = 1564 blocks, 8-lane record
// groups (50k concurrent streams), 3-stage software pipeline
// (record prefetch -> xt gather -> ds_add commit).
// R1 lesson: global fp32 atomics write through to HBM (204.8 MB).
// R2 lesson: random 8B global scatter costs a 64B line each; 1-block scan serializes.
// R3 lesson: 391-block accum = latency-starved (occ 25%, VALU 3%, HBM 2%).

#define BATCH  32
#define ROWB   128            // dst rows per bucket
#define KP     512            // padded max bucket count (M <= 65536)
#define EPB    8192           // edges per fill block
#define FILL_T 512
#define ACC_T  256

// ---- x (B,N) -> xt (N,B), LDS tiled ----
__global__ void k_transpose_x(const float* __restrict__ x, float* __restrict__ xt, int N) {
    __shared__ float tile[32][33];
    const int n0 = blockIdx.x * 32;
    const int tx = threadIdx.x;
    const int ty = threadIdx.y;
    #pragma unroll
    for (int k = 0; k < 4; ++k) {
        const int b = ty + 8 * k;
        const int n = n0 + tx;
        tile[tx][b] = (n < N) ? x[(size_t)b * N + n] : 0.0f;
    }
    __syncthreads();
    #pragma unroll
    for (int k = 0; k < 4; ++k) {
        const int n = n0 + ty + 8 * k;
        if (n < N) xt[(size_t)n * BATCH + tx] = tile[ty + 8 * k][tx];
    }
}

// ---- bucket counts (LDS-privatized histogram over K buckets) ----
__global__ void k_count(const int* __restrict__ idx, int* __restrict__ cnt, int E, int K) {
    __shared__ int h[KP];
    for (int i = threadIdx.x; i < K; i += blockDim.x) h[i] = 0;
    __syncthreads();
    const int stride = gridDim.x * blockDim.x;
    for (int e = blockIdx.x * blockDim.x + threadIdx.x; e < E; e += stride)
        atomicAdd(&h[idx[E + e] >> 7], 1);
    __syncthreads();
    for (int i = threadIdx.x; i < K; i += blockDim.x)
        if (h[i]) atomicAdd(&cnt[i], h[i]);
}

// ---- exclusive scan over K (<=512) bucket counts; one block of 512 ----
__global__ void k_scan(const int* __restrict__ cnt, int* __restrict__ start,
                       int* __restrict__ cursor, int K, int E) {
    __shared__ int sa[KP], sb[KP];
    const int t = threadIdx.x;               // 512 threads
    const int v = (t < K) ? cnt[t] : 0;
    sa[t] = v;
    __syncthreads();
    int* a = sa; int* b = sb;
    for (int off = 1; off < KP; off <<= 1) {
        b[t] = a[t] + ((t >= off) ? a[t - off] : 0);
        __syncthreads();
        int* tmp = a; a = b; b = tmp;
    }
    const int excl = a[t] - v;               // a = inclusive scan
    if (t < K) { start[t] = excl; cursor[t] = excl; }
    if (t == K - 1) start[K] = a[t];         // == E
}

// ---- fill: LDS-staged grouping by bucket, grouped coalesced flush ----
__global__ void k_fill(const int* __restrict__ idx, const float* __restrict__ values,
                       int* __restrict__ cursor, int2* __restrict__ records, int E, int K) {
    __shared__ int2 stage[EPB];              // 64 KB
    __shared__ int sa[KP], sb[KP];           // scan double-buffer
    __shared__ int lscan[KP + 1];
    __shared__ int lgbase[KP];

    const int t = threadIdx.x;               // 512
    const int base = blockIdx.x * EPB;
    const int total = min(EPB, E - base);

    sa[t] = 0;
    __syncthreads();
    // phase 1: local histogram
    for (int i = t; i < total; i += FILL_T)
        atomicAdd(&sa[idx[E + base + i] >> 7], 1);
    __syncthreads();
    const int myc = sa[t];                   // this thread's bucket count
    __syncthreads();
    // Hillis-Steele inclusive scan over KP entries
    int* a = sa; int* b = sb;
    for (int off = 1; off < KP; off <<= 1) {
        b[t] = a[t] + ((t >= off) ? a[t - off] : 0);
        __syncthreads();
        int* tmp = a; a = b; b = tmp;
    }
    lscan[t] = a[t] - myc;                   // exclusive; == total for t >= K
    if (t == 0) lscan[KP] = total;
    // reserve global range for this (block,bucket); reuse dead scan buffer as lcur
    int* lcur = b;
    lcur[t] = 0;
    lgbase[t] = (t < K && myc > 0) ? atomicAdd(&cursor[t], myc) : 0;
    __syncthreads();
    // phase 2: re-read edges, place grouped-by-bucket into LDS staging
    for (int i = t; i < total; i += FILL_T) {
        const int e = base + i;
        const int src = idx[e];
        const int dst = idx[E + e];
        const float v = values[e];
        const int bk = dst >> 7;
        const int pos = lscan[bk] + atomicAdd(&lcur[bk], 1);
        stage[pos] = make_int2(src | ((dst & 127) << 16), __float_as_int(v));
    }
    __syncthreads();
    // phase 3: flush — consecutive staging slots within a bucket map to
    // consecutive global addresses (chunks of ~EPB/K records)
    for (int i = t; i < total; i += FILL_T) {
        int bpos = 0;
        #pragma unroll
        for (int s = 256; s > 0; s >>= 1) {
            const int nb = bpos + s;
            if (nb < KP && lscan[nb] <= i) bpos = nb;
        }
        records[lgbase[bpos] + (i - lscan[bpos])] = stage[i];
    }
}

// ---- accum: block = (batch-octet, bucket); 8-lane record groups;
//      3-stage pipeline: record prefetch -> xt gather -> ds_add commit ----
__global__ void k_accum(const float* __restrict__ xt, const int2* __restrict__ records,
                        const int* __restrict__ start, const float* __restrict__ bias,
                        float* __restrict__ out, int M) {
    __shared__ float acc[ROWB * 9];          // 128 rows x 8 batch lanes (pad 9)
    const int t    = threadIdx.x;            // 256
    const int oct  = blockIdx.x;             // 0..3 (fastest: shares records in L2)
    const int bk   = blockIdx.y;             // bucket
    const int lane = t & 7;                  // batch lane within octet
    const int gid  = t >> 3;                 // 0..31 record-stream id
    const int b    = oct * 8 + lane;

    for (int i = t; i < ROWB * 9; i += ACC_T) acc[i] = 0.0f;
    __syncthreads();

    const int jb = start[bk], je = start[bk + 1];
    int j = jb + gid;
    int2 r0 = (j      < je) ? records[j]      : make_int2(0, 0);
    int2 r1 = (j + 32 < je) ? records[j + 32] : make_int2(0, 0);
    float xv0 = (j < je) ? xt[((size_t)(r0.x & 0xFFFF) << 5) + b] : 0.0f;
    while (j < je) {
        int2 r2 = (j + 64 < je) ? records[j + 64] : make_int2(0, 0);
        float xv1 = (j + 32 < je) ? xt[((size_t)(r1.x & 0xFFFF) << 5) + b] : 0.0f;
        atomicAdd(&acc[((r0.x >> 16) & 127) * 9 + lane], __int_as_float(r0.y) * xv0);
        r0 = r1; r1 = r2; xv0 = xv1;
        j += 32;
    }
    __syncthreads();

    const int m0 = bk * ROWB;
    for (int i = t; i < ROWB * 8; i += ACC_T) {
        const int mm = i & (ROWB - 1);
        const int bl = i >> 7;               // 0..7
        const int m  = m0 + mm;
        if (m < M) out[(size_t)(oct * 8 + bl) * M + m] = acc[mm * 9 + bl] + bias[m];
    }
}

extern "C" void kernel_launch(void* const* d_in, const int* in_sizes, int n_in,
                              void* d_out, int out_size, void* d_ws, size_t ws_size,
                              hipStream_t stream) {
    const float* x      = (const float*)d_in[0];  // (B,N,1) fp32
    const float* values = (const float*)d_in[1];  // (E,)    fp32
    const float* bias   = (const float*)d_in[2];  // (M,1)   fp32
    const int*   idx    = (const int*)d_in[3];    // (2,E)   int32

    const int N = in_sizes[0] / BATCH;   // 50000
    const int E = in_sizes[3] / 2;       // 1600000
    const int M = in_sizes[2];           // 50000
    const int K = (M + ROWB - 1) / ROWB; // 391

    float* out = (float*)d_out;

    // workspace: records (E int2, 12.8 MB) | xt (N*32 f32, 6.4 MB) | cnt | start | cursor
    char* p = (char*)d_ws;
    int2*  records = (int2*)p;           p += (size_t)E * sizeof(int2);
    float* xt      = (float*)p;          p += (size_t)N * BATCH * sizeof(float);
    int*   cnt     = (int*)p;            p += (size_t)K * sizeof(int);
    int*   start   = (int*)p;            p += (size_t)(K + 1) * sizeof(int);
    int*   cursor  = (int*)p;

    hipMemsetAsync(cnt, 0, (size_t)K * sizeof(int), stream);

    dim3 tblk(32, 8);
    k_transpose_x<<<(N + 31) / 32, tblk, 0, stream>>>(x, xt, N);
    k_count<<<256, 256, 0, stream>>>(idx, cnt, E, K);
    k_scan<<<1, KP, 0, stream>>>(cnt, start, cursor, K, E);
    k_fill<<<(E + EPB - 1) / EPB, FILL_T, 0, stream>>>(idx, values, cursor, records, E, K);

    dim3 agrid(4, K);
    k_accum<<<agrid, ACC_T, 0, stream>>>(xt, records, start, bias, out, M);
}